// Round 1
// baseline (798.840 us; speedup 1.0000x reference)
//
#include <hip/hip_runtime.h>

// SAGE 3-layer GNN, N=100000 nodes, E=1600000 edges, d: 64 -> 64 -> 64 -> 32.
// Strategy: build CSR (dst -> list of src) once per call, then each layer is a
// fused gather-aggregate + [self|mean] @ [W_self;W_neigh] GEMM (K=128) with
// weights staged in LDS. No float atomics anywhere.

#define NN 100000
#define NE 1600000

// ---------------- CSR construction ----------------

__global__ __launch_bounds__(256) void deg_count_kernel(
    const int* __restrict__ dst, int* __restrict__ deg, int n_edges) {
  int e = blockIdx.x * 256 + threadIdx.x;
  if (e < n_edges) atomicAdd(&deg[dst[e]], 1);
}

__global__ __launch_bounds__(256) void scan_partial_kernel(
    const int* __restrict__ deg, int* __restrict__ partials, int n_nodes) {
  __shared__ int sb[256];
  int t = threadIdx.x;
  int i = blockIdx.x * 256 + t;
  sb[t] = (i < n_nodes) ? deg[i] : 0;
  __syncthreads();
  for (int off = 128; off > 0; off >>= 1) {
    if (t < off) sb[t] += sb[t + off];
    __syncthreads();
  }
  if (t == 0) partials[blockIdx.x] = sb[0];
}

__global__ __launch_bounds__(512) void scan_top_kernel(
    int* __restrict__ partials, int nb, int* __restrict__ rowp, int n_nodes) {
  __shared__ int tmp[512];
  int t = threadIdx.x;
  int v = (t < nb) ? partials[t] : 0;
  tmp[t] = v;
  __syncthreads();
  for (int off = 1; off < 512; off <<= 1) {
    int add = (t >= off) ? tmp[t - off] : 0;
    __syncthreads();
    tmp[t] += add;
    __syncthreads();
  }
  if (t < nb) partials[t] = tmp[t] - v;      // exclusive block offsets
  if (t == 511) rowp[n_nodes] = tmp[511];    // total edge count
}

__global__ __launch_bounds__(256) void scan_final_kernel(
    const int* __restrict__ deg, const int* __restrict__ partials,
    int* __restrict__ rowp, int* __restrict__ cursor,
    float* __restrict__ degf, int n_nodes) {
  __shared__ int tmp[256];
  int t = threadIdx.x;
  int i = blockIdx.x * 256 + t;
  int v = (i < n_nodes) ? deg[i] : 0;
  tmp[t] = v;
  __syncthreads();
  for (int off = 1; off < 256; off <<= 1) {
    int add = (t >= off) ? tmp[t - off] : 0;
    __syncthreads();
    tmp[t] += add;
    __syncthreads();
  }
  if (i < n_nodes) {
    int exc = tmp[t] - v + partials[blockIdx.x];
    rowp[i] = exc;
    cursor[i] = exc;
    degf[i] = fmaxf((float)v, 1.0f);
  }
}

__global__ __launch_bounds__(256) void fill_kernel(
    const int* __restrict__ src, const int* __restrict__ dst,
    int* __restrict__ cursor, int* __restrict__ col, int n_edges) {
  int e = blockIdx.x * 256 + threadIdx.x;
  if (e < n_edges) {
    int pos = atomicAdd(&cursor[dst[e]], 1);
    col[pos] = src[e];
  }
}

// ---------------- fused layer: aggregate + dual GEMM ----------------
// block = 256 threads = 4 waves; each wave owns one node (grid covers N exactly).
// lane = input feature during aggregation, output column during GEMM.

template <int DOUT, bool RELU>
__global__ __launch_bounds__(256) void sage_layer_kernel(
    const float* __restrict__ h_in,       // [N, 64]
    const int* __restrict__ rowp,         // [N+1]
    const int* __restrict__ col,          // [E] source node ids
    const float* __restrict__ degf,       // [N] max(deg,1)
    const float* __restrict__ Wself,      // [64, DOUT]
    const float* __restrict__ Wneigh,     // [64, DOUT]
    const float* __restrict__ bias,       // [DOUT]
    float* __restrict__ h_out) {          // [N, DOUT]
  __shared__ float Wc[128 * DOUT];        // rows 0..63 = Wself, 64..127 = Wneigh
  __shared__ float rowbuf[4][128];        // per-wave [self(64) | mean(64)]

  int tid = threadIdx.x;
  for (int idx = tid; idx < 128 * DOUT; idx += 256) {
    int k = idx / DOUT, c = idx % DOUT;
    Wc[idx] = (k < 64) ? Wself[k * DOUT + c] : Wneigh[(k - 64) * DOUT + c];
  }

  int wave = tid >> 6;
  int lane = tid & 63;
  int n = blockIdx.x * 4 + wave;          // grid = N/4 exactly

  int e0 = rowp[n];
  int e1 = rowp[n + 1];
  float acc = 0.0f;
  int e = e0;
  // 4-way unroll: keep 4 row loads in flight to break the col->row latency chain
  for (; e + 3 < e1; e += 4) {
    int i0 = col[e], i1 = col[e + 1], i2 = col[e + 2], i3 = col[e + 3];
    float a0 = h_in[i0 * 64 + lane];
    float a1 = h_in[i1 * 64 + lane];
    float a2 = h_in[i2 * 64 + lane];
    float a3 = h_in[i3 * 64 + lane];
    acc += (a0 + a1) + (a2 + a3);
  }
  for (; e < e1; ++e) acc += h_in[col[e] * 64 + lane];

  float mean = acc / degf[n];             // IEEE divide, matches agg/max(deg,1)
  rowbuf[wave][lane] = h_in[n * 64 + lane];
  rowbuf[wave][64 + lane] = mean;
  __syncthreads();

  if (lane < DOUT) {
    float o = bias[lane];
#pragma unroll
    for (int k = 0; k < 128; ++k)
      o = fmaf(rowbuf[wave][k], Wc[k * DOUT + lane], o);
    if (RELU) o = fmaxf(o, 0.0f);
    h_out[n * DOUT + lane] = o;
  }
}

// ---------------- launch ----------------

extern "C" void kernel_launch(void* const* d_in, const int* in_sizes, int n_in,
                              void* d_out, int out_size, void* d_ws, size_t ws_size,
                              hipStream_t stream) {
  const float* x   = (const float*)d_in[0];
  const int*   src = (const int*)d_in[1];
  const int*   dst = (const int*)d_in[2];
  const float* Ws1 = (const float*)d_in[3];
  const float* Wn1 = (const float*)d_in[4];
  const float* b1  = (const float*)d_in[5];
  const float* Ws2 = (const float*)d_in[6];
  const float* Wn2 = (const float*)d_in[7];
  const float* b2  = (const float*)d_in[8];
  const float* Ws3 = (const float*)d_in[9];
  const float* Wn3 = (const float*)d_in[10];
  const float* b3  = (const float*)d_in[11];
  float* out = (float*)d_out;

  char* ws = (char*)d_ws;
  size_t off = 0;
  auto take = [&](size_t bytes) -> void* {
    void* p = ws + off;
    off += (bytes + 255) & ~(size_t)255;
    return p;
  };
  int*   deg      = (int*)take((size_t)NN * 4);
  float* degf     = (float*)take((size_t)NN * 4);
  int*   rowp     = (int*)take((size_t)(NN + 1) * 4);
  int*   cursor   = (int*)take((size_t)NN * 4);
  int*   partials = (int*)take(1024 * 4);
  int*   col      = (int*)take((size_t)NE * 4);
  float* h1       = (float*)take((size_t)NN * 64 * 4);
  float* h2       = (float*)take((size_t)NN * 64 * 4);
  (void)ws_size; (void)in_sizes; (void)n_in; (void)out_size;

  hipMemsetAsync(deg, 0, (size_t)NN * 4, stream);

  const int EB = (NE + 255) / 256;   // 6250
  const int NB = (NN + 255) / 256;   // 391

  deg_count_kernel<<<EB, 256, 0, stream>>>(dst, deg, NE);
  scan_partial_kernel<<<NB, 256, 0, stream>>>(deg, partials, NN);
  scan_top_kernel<<<1, 512, 0, stream>>>(partials, NB, rowp, NN);
  scan_final_kernel<<<NB, 256, 0, stream>>>(deg, partials, rowp, cursor, degf, NN);
  fill_kernel<<<EB, 256, 0, stream>>>(src, dst, cursor, col, NE);

  sage_layer_kernel<64, false><<<NN / 4, 256, 0, stream>>>(x,  rowp, col, degf, Ws1, Wn1, b1, h1);
  sage_layer_kernel<64, false><<<NN / 4, 256, 0, stream>>>(h1, rowp, col, degf, Ws2, Wn2, b2, h2);
  sage_layer_kernel<32, true ><<<NN / 4, 256, 0, stream>>>(h2, rowp, col, degf, Ws3, Wn3, b3, out);
}

// Round 3
// 642.337 us; speedup vs baseline: 1.2436x; 1.2436x over previous
//
#include <hip/hip_runtime.h>

// SAGE 3-layer GNN, N=100000 nodes, E=1600000 edges, d: 64 -> 64 -> 64 -> 32.
// CSR (dst -> srcs) built once per call; each layer = fused gather-mean +
// [self|mean] @ [W_self;W_neigh] (K=128) with transposed weights in LDS.
// Layer kernel is persistent (grid-stride): weights staged once per block,
// no barriers in the node loop (per-wave LDS slices only).

#define NN 100000
#define NE 1600000
#define GBLOCKS 1024

// ---------------- CSR construction ----------------

__global__ __launch_bounds__(256) void deg_count_kernel(
    const int* __restrict__ dst, int* __restrict__ deg, int n_edges) {
  int e = blockIdx.x * 256 + threadIdx.x;
  if (e < n_edges) atomicAdd(&deg[dst[e]], 1);
}

__global__ __launch_bounds__(256) void scan_partial_kernel(
    const int* __restrict__ deg, int* __restrict__ partials, int n_nodes) {
  __shared__ int sb[256];
  int t = threadIdx.x;
  int i = blockIdx.x * 256 + t;
  sb[t] = (i < n_nodes) ? deg[i] : 0;
  __syncthreads();
  for (int off = 128; off > 0; off >>= 1) {
    if (t < off) sb[t] += sb[t + off];
    __syncthreads();
  }
  if (t == 0) partials[blockIdx.x] = sb[0];
}

__global__ __launch_bounds__(512) void scan_top_kernel(
    int* __restrict__ partials, int nb, int* __restrict__ rowp, int n_nodes) {
  __shared__ int tmp[512];
  int t = threadIdx.x;
  int v = (t < nb) ? partials[t] : 0;
  tmp[t] = v;
  __syncthreads();
  for (int off = 1; off < 512; off <<= 1) {
    int add = (t >= off) ? tmp[t - off] : 0;
    __syncthreads();
    tmp[t] += add;
    __syncthreads();
  }
  if (t < nb) partials[t] = tmp[t] - v;      // exclusive block offsets
  if (t == 511) rowp[n_nodes] = tmp[511];    // total edge count
}

__global__ __launch_bounds__(256) void scan_final_kernel(
    const int* __restrict__ deg, const int* __restrict__ partials,
    int* __restrict__ rowp, int* __restrict__ cursor,
    float* __restrict__ degf, int n_nodes) {
  __shared__ int tmp[256];
  int t = threadIdx.x;
  int i = blockIdx.x * 256 + t;
  int v = (i < n_nodes) ? deg[i] : 0;
  tmp[t] = v;
  __syncthreads();
  for (int off = 1; off < 256; off <<= 1) {
    int add = (t >= off) ? tmp[t - off] : 0;
    __syncthreads();
    tmp[t] += add;
    __syncthreads();
  }
  if (i < n_nodes) {
    int exc = tmp[t] - v + partials[blockIdx.x];
    rowp[i] = exc;
    cursor[i] = exc;
    degf[i] = fmaxf((float)v, 1.0f);
  }
}

__global__ __launch_bounds__(256) void fill_kernel(
    const int* __restrict__ src, const int* __restrict__ dst,
    int* __restrict__ cursor, int* __restrict__ col, int n_edges) {
  int e = blockIdx.x * 256 + threadIdx.x;
  if (e < n_edges) {
    int pos = atomicAdd(&cursor[dst[e]], 1);
    col[pos] = src[e];
  }
}

// ---------------- fused layer: aggregate + dual GEMM ----------------
// 256 threads = 4 waves, wave owns one node per grid-stride iteration.
// Edge gather: 64 col indices loaded coalesced into per-wave LDS, consumed
// 8-wide with readfirstlane -> scalar-base row loads (8 loads in flight).
// GEMM: Wt[c][k] transposed+padded in LDS, ds_read_b128, 4 partial accs.

template <int DOUT, bool RELU>
__global__ __launch_bounds__(256) void sage_layer_kernel(
    const float* __restrict__ h_in,       // [N, 64]
    const int* __restrict__ rowp,         // [N+1]
    const int* __restrict__ col,          // [E]
    const float* __restrict__ degf,       // [N] max(deg,1)
    const float* __restrict__ Wself,      // [64, DOUT]
    const float* __restrict__ Wneigh,     // [64, DOUT]
    const float* __restrict__ bias,       // [DOUT]
    float* __restrict__ h_out) {          // [N, DOUT]
  __shared__ float Wt[DOUT][132];         // Wt[c][k] = Wcat[k][c], pad->132
  __shared__ float rowbuf[4][128];        // per-wave [self(64)|mean(64)]
  __shared__ int   idxbuf[4][64];         // per-wave staged col indices

  const int tid  = threadIdx.x;
  const int wave = tid >> 6;
  const int lane = tid & 63;

  // stage transposed weights once per block (coalesced global reads)
  for (int idx = tid; idx < DOUT * 128; idx += 256) {
    int c = idx & (DOUT - 1);
    int k = idx / DOUT;
    Wt[c][k] = (k < 64) ? Wself[k * DOUT + c] : Wneigh[(k - 64) * DOUT + c];
  }
  __syncthreads();

  const float bval = (lane < DOUT) ? bias[lane] : 0.0f;

  for (int g = blockIdx.x; g < NN / 4; g += GBLOCKS) {
    const int   un   = __builtin_amdgcn_readfirstlane(g * 4 + wave);
    const int   e0   = rowp[un];
    const int   e1   = rowp[un + 1];
    const float self = h_in[un * 64 + lane];   // scalar-base, hides under loop

    float acc = 0.0f;
    for (int base = e0; base < e1; base += 64) {
      // coalesced index stage; invalid slots -> node 0 (safe, value-masked)
      idxbuf[wave][lane] = (base + lane < e1) ? col[base + lane] : 0;
      const int m = min(64, e1 - base);
      for (int j = 0; j < m; j += 8) {
        const int4 q0 = *(const int4*)&idxbuf[wave][j];
        const int4 q1 = *(const int4*)&idxbuf[wave][j + 4];
        const float* p0 = h_in + __builtin_amdgcn_readfirstlane(q0.x) * 64;
        const float* p1 = h_in + __builtin_amdgcn_readfirstlane(q0.y) * 64;
        const float* p2 = h_in + __builtin_amdgcn_readfirstlane(q0.z) * 64;
        const float* p3 = h_in + __builtin_amdgcn_readfirstlane(q0.w) * 64;
        const float* p4 = h_in + __builtin_amdgcn_readfirstlane(q1.x) * 64;
        const float* p5 = h_in + __builtin_amdgcn_readfirstlane(q1.y) * 64;
        const float* p6 = h_in + __builtin_amdgcn_readfirstlane(q1.z) * 64;
        const float* p7 = h_in + __builtin_amdgcn_readfirstlane(q1.w) * 64;
        float a0 = p0[lane];
        float a1 = p1[lane];
        float a2 = p2[lane];
        float a3 = p3[lane];
        float a4 = p4[lane];
        float a5 = p5[lane];
        float a6 = p6[lane];
        float a7 = p7[lane];
        a0 = (j + 0 < m) ? a0 : 0.0f;
        a1 = (j + 1 < m) ? a1 : 0.0f;
        a2 = (j + 2 < m) ? a2 : 0.0f;
        a3 = (j + 3 < m) ? a3 : 0.0f;
        a4 = (j + 4 < m) ? a4 : 0.0f;
        a5 = (j + 5 < m) ? a5 : 0.0f;
        a6 = (j + 6 < m) ? a6 : 0.0f;
        a7 = (j + 7 < m) ? a7 : 0.0f;
        acc += ((a0 + a1) + (a2 + a3)) + ((a4 + a5) + (a6 + a7));
      }
    }

    rowbuf[wave][lane]      = self;
    rowbuf[wave][64 + lane] = acc / degf[un];
    // per-wave LDS only: no __syncthreads needed (compiler inserts lgkmcnt)

    if (lane < DOUT) {
      float o0 = 0.f, o1 = 0.f, o2 = 0.f, o3 = 0.f;
#pragma unroll
      for (int j = 0; j < 32; ++j) {
        const float4 w = *(const float4*)&Wt[lane][j * 4];
        const float4 r = *(const float4*)&rowbuf[wave][j * 4];
        o0 = fmaf(r.x, w.x, o0);
        o1 = fmaf(r.y, w.y, o1);
        o2 = fmaf(r.z, w.z, o2);
        o3 = fmaf(r.w, w.w, o3);
      }
      float o = ((o0 + o1) + (o2 + o3)) + bval;
      if (RELU) o = fmaxf(o, 0.0f);
      h_out[un * DOUT + lane] = o;
    }
  }
}

// ---------------- launch ----------------

extern "C" void kernel_launch(void* const* d_in, const int* in_sizes, int n_in,
                              void* d_out, int out_size, void* d_ws, size_t ws_size,
                              hipStream_t stream) {
  const float* x   = (const float*)d_in[0];
  const int*   src = (const int*)d_in[1];
  const int*   dst = (const int*)d_in[2];
  const float* Ws1 = (const float*)d_in[3];
  const float* Wn1 = (const float*)d_in[4];
  const float* b1  = (const float*)d_in[5];
  const float* Ws2 = (const float*)d_in[6];
  const float* Wn2 = (const float*)d_in[7];
  const float* b2  = (const float*)d_in[8];
  const float* Ws3 = (const float*)d_in[9];
  const float* Wn3 = (const float*)d_in[10];
  const float* b3  = (const float*)d_in[11];
  float* out = (float*)d_out;

  char* ws = (char*)d_ws;
  size_t off = 0;
  auto take = [&](size_t bytes) -> void* {
    void* p = ws + off;
    off += (bytes + 255) & ~(size_t)255;
    return p;
  };
  int*   deg      = (int*)take((size_t)NN * 4);
  float* degf     = (float*)take((size_t)NN * 4);
  int*   rowp     = (int*)take((size_t)(NN + 1) * 4);
  int*   cursor   = (int*)take((size_t)NN * 4);
  int*   partials = (int*)take(1024 * 4);
  int*   col      = (int*)take((size_t)NE * 4);
  float* h1       = (float*)take((size_t)NN * 64 * 4);
  float* h2       = (float*)take((size_t)NN * 64 * 4);
  (void)ws_size; (void)in_sizes; (void)n_in; (void)out_size;

  hipMemsetAsync(deg, 0, (size_t)NN * 4, stream);

  const int EB = (NE + 255) / 256;   // 6250
  const int NB = (NN + 255) / 256;   // 391

  deg_count_kernel<<<EB, 256, 0, stream>>>(dst, deg, NE);
  scan_partial_kernel<<<NB, 256, 0, stream>>>(deg, partials, NN);
  scan_top_kernel<<<1, 512, 0, stream>>>(partials, NB, rowp, NN);
  scan_final_kernel<<<NB, 256, 0, stream>>>(deg, partials, rowp, cursor, degf, NN);
  fill_kernel<<<EB, 256, 0, stream>>>(src, dst, cursor, col, NE);

  sage_layer_kernel<64, false><<<GBLOCKS, 256, 0, stream>>>(x,  rowp, col, degf, Ws1, Wn1, b1, h1);
  sage_layer_kernel<64, false><<<GBLOCKS, 256, 0, stream>>>(h1, rowp, col, degf, Ws2, Wn2, b2, h2);
  sage_layer_kernel<32, true ><<<GBLOCKS, 256, 0, stream>>>(h2, rowp, col, degf, Ws3, Wn3, b3, out);
}

// Round 8
// 619.923 us; speedup vs baseline: 1.2886x; 1.0362x over previous
//
#include <hip/hip_runtime.h>

// SAGE 3-layer GNN, N=100000 nodes, E=1600000 edges, d: 64 -> 64 -> 64 -> 32.
// CSR (dst -> srcs) built once per call. Per layer, two kernels:
//  1) agg_mean: gather-mean over in-neighbors. 4 nodes per wave (one per
//     16-lane group), float4 per lane -> each load instr fetches 4 rows;
//     8-deep unroll keeps 8 row loads in flight; zero LDS -> high occupancy.
//  2) gemm: [self|mean] @ [W_self;W_neigh] + bias (+relu), persistent blocks,
//     transposed weights staged once per block in LDS.

#define NN 100000
#define NE 1600000
#define GEMM_BLOCKS 1024

// ---------------- CSR construction ----------------

__global__ __launch_bounds__(256) void deg_count_kernel(
    const int* __restrict__ dst, int* __restrict__ deg, int n_edges) {
  int e = blockIdx.x * 256 + threadIdx.x;
  if (e < n_edges) atomicAdd(&deg[dst[e]], 1);
}

__global__ __launch_bounds__(256) void scan_partial_kernel(
    const int* __restrict__ deg, int* __restrict__ partials, int n_nodes) {
  __shared__ int sb[256];
  int t = threadIdx.x;
  int i = blockIdx.x * 256 + t;
  sb[t] = (i < n_nodes) ? deg[i] : 0;
  __syncthreads();
  for (int off = 128; off > 0; off >>= 1) {
    if (t < off) sb[t] += sb[t + off];
    __syncthreads();
  }
  if (t == 0) partials[blockIdx.x] = sb[0];
}

__global__ __launch_bounds__(512) void scan_top_kernel(
    int* __restrict__ partials, int nb, int* __restrict__ rowp, int n_nodes) {
  __shared__ int tmp[512];
  int t = threadIdx.x;
  int v = (t < nb) ? partials[t] : 0;
  tmp[t] = v;
  __syncthreads();
  for (int off = 1; off < 512; off <<= 1) {
    int add = (t >= off) ? tmp[t - off] : 0;
    __syncthreads();
    tmp[t] += add;
    __syncthreads();
  }
  if (t < nb) partials[t] = tmp[t] - v;      // exclusive block offsets
  if (t == 511) rowp[n_nodes] = tmp[511];    // total edge count
}

__global__ __launch_bounds__(256) void scan_final_kernel(
    const int* __restrict__ deg, const int* __restrict__ partials,
    int* __restrict__ rowp, int* __restrict__ cursor,
    float* __restrict__ degf, int n_nodes) {
  __shared__ int tmp[256];
  int t = threadIdx.x;
  int i = blockIdx.x * 256 + t;
  int v = (i < n_nodes) ? deg[i] : 0;
  tmp[t] = v;
  __syncthreads();
  for (int off = 1; off < 256; off <<= 1) {
    int add = (t >= off) ? tmp[t - off] : 0;
    __syncthreads();
    tmp[t] += add;
    __syncthreads();
  }
  if (i < n_nodes) {
    int exc = tmp[t] - v + partials[blockIdx.x];
    rowp[i] = exc;
    cursor[i] = exc;
    degf[i] = fmaxf((float)v, 1.0f);
  }
}

__global__ __launch_bounds__(256) void fill_kernel(
    const int* __restrict__ src, const int* __restrict__ dst,
    int* __restrict__ cursor, int* __restrict__ col, int n_edges) {
  int e = blockIdx.x * 256 + threadIdx.x;
  if (e < n_edges) {
    int pos = atomicAdd(&cursor[dst[e]], 1);
    col[pos] = src[e];
  }
}

// ---------------- aggregation: mean over in-neighbors ----------------
// 256 threads = 4 waves; each wave handles 4 nodes (16-lane group per node).
// lane = 16*g + q: group g's node, features [4q, 4q+3] as float4.
// One load instruction fetches 4 rows (one per group) -> 1.5 VALU/edge and
// 8 row-gathers in flight per wave. No LDS.

__global__ __launch_bounds__(256) void agg_mean_kernel(
    const float* __restrict__ h_in,      // [N, 64]
    const int* __restrict__ rowp,        // [N+1]
    const int* __restrict__ col,         // [E]
    const float* __restrict__ degf,      // [N] max(deg,1)
    float* __restrict__ mean_out) {      // [N, 64]
  const int tid  = threadIdx.x;
  const int wave = tid >> 6;
  const int lane = tid & 63;
  const int g    = lane >> 4;            // node slot 0..3
  const int f4   = (lane & 15) * 4;      // feature offset

  const int n = blockIdx.x * 16 + wave * 4 + g;   // grid covers NN exactly

  const int e0 = rowp[n];
  const int e1 = rowp[n + 1];
  const int ecount = e1 - e0;

  float4 acc = {0.f, 0.f, 0.f, 0.f};
  int e = 0;
  // full 8-edge bodies, unmasked
  for (; e + 8 <= ecount; e += 8) {
    int i0 = col[e0 + e + 0], i1 = col[e0 + e + 1];
    int i2 = col[e0 + e + 2], i3 = col[e0 + e + 3];
    int i4 = col[e0 + e + 4], i5 = col[e0 + e + 5];
    int i6 = col[e0 + e + 6], i7 = col[e0 + e + 7];
    float4 v0 = *(const float4*)(h_in + (size_t)i0 * 64 + f4);
    float4 v1 = *(const float4*)(h_in + (size_t)i1 * 64 + f4);
    float4 v2 = *(const float4*)(h_in + (size_t)i2 * 64 + f4);
    float4 v3 = *(const float4*)(h_in + (size_t)i3 * 64 + f4);
    float4 v4 = *(const float4*)(h_in + (size_t)i4 * 64 + f4);
    float4 v5 = *(const float4*)(h_in + (size_t)i5 * 64 + f4);
    float4 v6 = *(const float4*)(h_in + (size_t)i6 * 64 + f4);
    float4 v7 = *(const float4*)(h_in + (size_t)i7 * 64 + f4);
    acc.x += ((v0.x + v1.x) + (v2.x + v3.x)) + ((v4.x + v5.x) + (v6.x + v7.x));
    acc.y += ((v0.y + v1.y) + (v2.y + v3.y)) + ((v4.y + v5.y) + (v6.y + v7.y));
    acc.z += ((v0.z + v1.z) + (v2.z + v3.z)) + ((v4.z + v5.z) + (v6.z + v7.z));
    acc.w += ((v0.w + v1.w) + (v2.w + v3.w)) + ((v4.w + v5.w) + (v6.w + v7.w));
  }
  // one masked tail body (indices clamped to a valid edge, values masked)
  if (e < ecount) {
    const int last = e1 - 1;
#pragma unroll
    for (int u = 0; u < 8; ++u) {
      int ee = e0 + e + u;
      int ii = col[ee <= last ? ee : last];
      float4 v = *(const float4*)(h_in + (size_t)ii * 64 + f4);
      float msk = (e + u < ecount) ? 1.0f : 0.0f;
      acc.x = fmaf(v.x, msk, acc.x);
      acc.y = fmaf(v.y, msk, acc.y);
      acc.z = fmaf(v.z, msk, acc.z);
      acc.w = fmaf(v.w, msk, acc.w);
    }
  }

  const float d = degf[n];
  float4 mv = {acc.x / d, acc.y / d, acc.z / d, acc.w / d};
  *(float4*)(mean_out + (size_t)n * 64 + f4) = mv;
}

// ---------------- dual GEMM: [self|mean] @ [Wself;Wneigh] + b ----------------
// persistent blocks; Wt[c][k] transposed+padded staged once per block.

template <int DOUT, bool RELU>
__global__ __launch_bounds__(256) void gemm_kernel(
    const float* __restrict__ h_self,     // [N, 64]
    const float* __restrict__ mean,       // [N, 64]
    const float* __restrict__ Wself,      // [64, DOUT]
    const float* __restrict__ Wneigh,     // [64, DOUT]
    const float* __restrict__ bias,       // [DOUT]
    float* __restrict__ h_out) {          // [N, DOUT]
  __shared__ float Wt[DOUT][132];         // Wt[c][k] = Wcat[k][c]
  __shared__ float rowbuf[4][128];        // per-wave [self(64)|mean(64)]

  const int tid  = threadIdx.x;
  const int wave = tid >> 6;
  const int lane = tid & 63;

  for (int idx = tid; idx < DOUT * 128; idx += 256) {
    int c = idx & (DOUT - 1);
    int k = idx / DOUT;
    Wt[c][k] = (k < 64) ? Wself[k * DOUT + c] : Wneigh[(k - 64) * DOUT + c];
  }
  __syncthreads();

  const float bval = (lane < DOUT) ? bias[lane] : 0.0f;

  for (int gblk = blockIdx.x; gblk < NN / 4; gblk += GEMM_BLOCKS) {
    const int n = gblk * 4 + wave;
    rowbuf[wave][lane]      = h_self[(size_t)n * 64 + lane];
    rowbuf[wave][64 + lane] = mean[(size_t)n * 64 + lane];
    // per-wave LDS only: compiler-inserted lgkmcnt orders write->read

    if (lane < DOUT) {
      float o0 = 0.f, o1 = 0.f, o2 = 0.f, o3 = 0.f;
#pragma unroll
      for (int j = 0; j < 32; ++j) {
        const float4 w = *(const float4*)&Wt[lane][j * 4];
        const float4 r = *(const float4*)&rowbuf[wave][j * 4];
        o0 = fmaf(r.x, w.x, o0);
        o1 = fmaf(r.y, w.y, o1);
        o2 = fmaf(r.z, w.z, o2);
        o3 = fmaf(r.w, w.w, o3);
      }
      float o = ((o0 + o1) + (o2 + o3)) + bval;
      if (RELU) o = fmaxf(o, 0.0f);
      h_out[(size_t)n * DOUT + lane] = o;
    }
  }
}

// ---------------- launch ----------------

extern "C" void kernel_launch(void* const* d_in, const int* in_sizes, int n_in,
                              void* d_out, int out_size, void* d_ws, size_t ws_size,
                              hipStream_t stream) {
  const float* x   = (const float*)d_in[0];
  const int*   src = (const int*)d_in[1];
  const int*   dst = (const int*)d_in[2];
  const float* Ws1 = (const float*)d_in[3];
  const float* Wn1 = (const float*)d_in[4];
  const float* b1  = (const float*)d_in[5];
  const float* Ws2 = (const float*)d_in[6];
  const float* Wn2 = (const float*)d_in[7];
  const float* b2  = (const float*)d_in[8];
  const float* Ws3 = (const float*)d_in[9];
  const float* Wn3 = (const float*)d_in[10];
  const float* b3  = (const float*)d_in[11];
  float* out = (float*)d_out;

  char* ws = (char*)d_ws;
  size_t off = 0;
  auto take = [&](size_t bytes) -> void* {
    void* p = ws + off;
    off += (bytes + 255) & ~(size_t)255;
    return p;
  };
  int*   deg      = (int*)take((size_t)NN * 4);
  float* degf     = (float*)take((size_t)NN * 4);
  int*   rowp     = (int*)take((size_t)(NN + 1) * 4);
  int*   cursor   = (int*)take((size_t)NN * 4);
  int*   partials = (int*)take(1024 * 4);
  int*   col      = (int*)take((size_t)NE * 4);
  float* h1       = (float*)take((size_t)NN * 64 * 4);
  float* h2       = (float*)take((size_t)NN * 64 * 4);
  float* meanbuf  = (float*)take((size_t)NN * 64 * 4);
  (void)ws_size; (void)in_sizes; (void)n_in; (void)out_size;

  hipMemsetAsync(deg, 0, (size_t)NN * 4, stream);

  const int EB = (NE + 255) / 256;   // 6250
  const int NB = (NN + 255) / 256;   // 391
  const int AB = NN / 16;            // 6250 blocks, 16 nodes each

  deg_count_kernel<<<EB, 256, 0, stream>>>(dst, deg, NE);
  scan_partial_kernel<<<NB, 256, 0, stream>>>(deg, partials, NN);
  scan_top_kernel<<<1, 512, 0, stream>>>(partials, NB, rowp, NN);
  scan_final_kernel<<<NB, 256, 0, stream>>>(deg, partials, rowp, cursor, degf, NN);
  fill_kernel<<<EB, 256, 0, stream>>>(src, dst, cursor, col, NE);

  agg_mean_kernel<<<AB, 256, 0, stream>>>(x, rowp, col, degf, meanbuf);
  gemm_kernel<64, false><<<GEMM_BLOCKS, 256, 0, stream>>>(x, meanbuf, Ws1, Wn1, b1, h1);

  agg_mean_kernel<<<AB, 256, 0, stream>>>(h1, rowp, col, degf, meanbuf);
  gemm_kernel<64, false><<<GEMM_BLOCKS, 256, 0, stream>>>(h1, meanbuf, Ws2, Wn2, b2, h2);

  agg_mean_kernel<<<AB, 256, 0, stream>>>(h2, rowp, col, degf, meanbuf);
  gemm_kernel<32, true ><<<GEMM_BLOCKS, 256, 0, stream>>>(h2, meanbuf, Ws3, Wn3, b3, out);
}